// Round 1
// baseline (29.800 us; speedup 1.0000x reference)
//
#include <hip/hip_runtime.h>

// ContrastiveCenterLoss on MI355X.
// B=2048 rows of feat (D=512), C=100 class centers, int labels, scalar loss.
//
// Algebra (avoids the (B,C) distance matrix entirely):
//   sum_all  = C*Sf2 + B*Sc2 - 2*dot(sumF, sumC)
//   intra    = sum_b ( ||f_b||^2 + ||c_lab||^2 - 2 f_b . c_lab )
//   inter    = sum_all - intra
//   loss     = 0.5/B * intra / (inter + 1e-6) / 0.1
//
// ws layout (floats): [0]=intra  [1]=Sf2  [2]=Sc2  [3..514]=sumF  [515..1026]=sumC

#define WS_INTRA 0
#define WS_SF2   1
#define WS_SC2   2
#define WS_SUMF  3
#define WS_SUMC  (3 + 512)

__global__ __launch_bounds__(256) void ccl_main(
        const float* __restrict__ feat,
        const float* __restrict__ weight,
        const int*   __restrict__ label,
        float* __restrict__ ws,
        int B, int C, int featBlocks, int weightBlocks)
{
    __shared__ float lsum[512];
    const int tid  = threadIdx.x;
    const int lane = tid & 63;
    const int wave = tid >> 6;

    lsum[tid]       = 0.f;
    lsum[tid + 256] = 0.f;
    __syncthreads();

    float acc0 = 0.f, acc1 = 0.f, acc2 = 0.f, acc3 = 0.f;
    float acc4 = 0.f, acc5 = 0.f, acc6 = 0.f, acc7 = 0.f;
    float s2_local    = 0.f;   // partial of Sf2 (feat blocks) or Sc2 (weight blocks)
    float intra_local = 0.f;

    const bool isFeat = (int)blockIdx.x < featBlocks;

    if (isFeat) {
        const int wavesTotal = featBlocks * 4;
        const int gwave      = blockIdx.x * 4 + wave;
        for (int row = gwave; row < B; row += wavesTotal) {
            const float4* fr = (const float4*)(feat + (size_t)row * 512);
            float4 a = fr[lane];
            float4 b = fr[lane + 64];
            const int lab = label[row];
            const float4* wr = (const float4*)(weight + (size_t)lab * 512);
            float4 wa = wr[lane];
            float4 wb = wr[lane + 64];

            float f2 = a.x*a.x + a.y*a.y + a.z*a.z + a.w*a.w
                     + b.x*b.x + b.y*b.y + b.z*b.z + b.w*b.w;
            float w2 = wa.x*wa.x + wa.y*wa.y + wa.z*wa.z + wa.w*wa.w
                     + wb.x*wb.x + wb.y*wb.y + wb.z*wb.z + wb.w*wb.w;
            float dt = a.x*wa.x + a.y*wa.y + a.z*wa.z + a.w*wa.w
                     + b.x*wb.x + b.y*wb.y + b.z*wb.z + b.w*wb.w;

            acc0 += a.x; acc1 += a.y; acc2 += a.z; acc3 += a.w;
            acc4 += b.x; acc5 += b.y; acc6 += b.z; acc7 += b.w;

            float t = f2 + w2 - 2.f * dt;   // this row's contribution to intra
            #pragma unroll
            for (int off = 32; off > 0; off >>= 1) {
                t  += __shfl_xor(t,  off);
                f2 += __shfl_xor(f2, off);
            }
            if (lane == 0) { intra_local += t; s2_local += f2; }
        }
    } else {
        const int wavesTotal = weightBlocks * 4;
        const int gwave      = (blockIdx.x - featBlocks) * 4 + wave;
        for (int row = gwave; row < C; row += wavesTotal) {
            const float4* wr = (const float4*)(weight + (size_t)row * 512);
            float4 a = wr[lane];
            float4 b = wr[lane + 64];
            float w2 = a.x*a.x + a.y*a.y + a.z*a.z + a.w*a.w
                     + b.x*b.x + b.y*b.y + b.z*b.z + b.w*b.w;

            acc0 += a.x; acc1 += a.y; acc2 += a.z; acc3 += a.w;
            acc4 += b.x; acc5 += b.y; acc6 += b.z; acc7 += b.w;

            #pragma unroll
            for (int off = 32; off > 0; off >>= 1) w2 += __shfl_xor(w2, off);
            if (lane == 0) s2_local += w2;
        }
    }

    // Block-reduce the per-lane column sums into LDS.
    // Lane l owns dims [4l..4l+3] and [256+4l..256+4l+3] (same mapping in every wave).
    atomicAdd(&lsum[4*lane + 0],   acc0);
    atomicAdd(&lsum[4*lane + 1],   acc1);
    atomicAdd(&lsum[4*lane + 2],   acc2);
    atomicAdd(&lsum[4*lane + 3],   acc3);
    atomicAdd(&lsum[256 + 4*lane + 0], acc4);
    atomicAdd(&lsum[256 + 4*lane + 1], acc5);
    atomicAdd(&lsum[256 + 4*lane + 2], acc6);
    atomicAdd(&lsum[256 + 4*lane + 3], acc7);
    __syncthreads();

    float* gsum = isFeat ? (ws + WS_SUMF) : (ws + WS_SUMC);
    atomicAdd(&gsum[tid],       lsum[tid]);
    atomicAdd(&gsum[tid + 256], lsum[tid + 256]);

    if (lane == 0) {
        if (isFeat) {
            atomicAdd(&ws[WS_INTRA], intra_local);
            atomicAdd(&ws[WS_SF2],   s2_local);
        } else {
            atomicAdd(&ws[WS_SC2],   s2_local);
        }
    }
}

__global__ void ccl_final(const float* __restrict__ ws, float* __restrict__ out,
                          int B, int C)
{
    const int lane = threadIdx.x;
    float dot = 0.f;
    #pragma unroll
    for (int k = 0; k < 8; ++k) {
        int d = lane + 64 * k;
        dot += ws[WS_SUMF + d] * ws[WS_SUMC + d];
    }
    #pragma unroll
    for (int off = 32; off > 0; off >>= 1) dot += __shfl_xor(dot, off);

    if (lane == 0) {
        float intra = ws[WS_INTRA];
        float Sf2   = ws[WS_SF2];
        float Sc2   = ws[WS_SC2];
        float total = (float)C * Sf2 + (float)B * Sc2 - 2.f * dot;
        float inter = total - intra;
        float loss  = 0.5f / (float)B * intra / (inter + 1e-6f) / 0.1f;
        out[0] = loss;
    }
}

extern "C" void kernel_launch(void* const* d_in, const int* in_sizes, int n_in,
                              void* d_out, int out_size, void* d_ws, size_t ws_size,
                              hipStream_t stream) {
    const float* feat   = (const float*)d_in[0];
    const float* weight = (const float*)d_in[1];
    const int*   label  = (const int*)d_in[2];
    float* out = (float*)d_out;
    float* ws  = (float*)d_ws;

    const int B = in_sizes[2];              // 2048
    const int D = in_sizes[0] / B;          // 512
    const int C = in_sizes[1] / D;          // 100
    (void)D;                                // kernel specialized for D=512

    // Zero the accumulator region (ws is poisoned 0xAA and not re-poisoned
    // between timed replays).
    hipMemsetAsync(d_ws, 0, (3 + 2 * 512) * sizeof(float), stream);

    const int FEAT_BLOCKS   = 64;
    const int WEIGHT_BLOCKS = 4;
    ccl_main<<<FEAT_BLOCKS + WEIGHT_BLOCKS, 256, 0, stream>>>(
        feat, weight, label, ws, B, C, FEAT_BLOCKS, WEIGHT_BLOCKS);
    ccl_final<<<1, 64, 0, stream>>>(ws, out, B, C);
}